// Round 8
// baseline (251.589 us; speedup 1.0000x reference)
//
#include <hip/hip_runtime.h>

// RankModelF: BATCH=1e6 rows. Each row: gather 9 embeddings (21x3 table),
// 8 L2 distances, s = exp(-10 d) + 1e-3, T = sum(s),
// prob[k] for k in 0..55: (i,j) = perms(8,2)[k]; prob = s_i/T * s_j/(T - s_i)
//                       = c_i * s_j, c_i = s_i / (T*(T - s_i)).
// Memory-bound: 36 MB read + 224 MB write => ~41 us floor @6.3 TB/s.
// Output is write-once streaming -> nontemporal stores (nt) to spare L2.

#define BATCH_N   1000000
#define ROWS      256      // rows per block
#define TPB       256
#define NOUT      56       // permutations(8,2)
#define NOUT4     14       // NOUT/4 float4 per row
#define SVP       17       // padded row stride for s_sv (breaks 16-bank alias, G4)

typedef float f32x4 __attribute__((ext_vector_type(4)));  // native vec for nt-store

__global__ __launch_bounds__(TPB) void rank_model_kernel(
    const int*  __restrict__ stim,   // (BATCH, 9) int32
    const float* __restrict__ emb,   // (21, 3) f32
    float*      __restrict__ out)    // (BATCH, 56) f32
{
    __shared__ float s_emb[21 * 3];          // 63 floats
    __shared__ int   s_stim[ROWS * 9];       // staged indices
    __shared__ float s_sv[ROWS][SVP];        // per row: s[0..7], c[0..7], pad

    const unsigned t     = threadIdx.x;
    const unsigned row0  = blockIdx.x * ROWS;
    const int      nrows = min((int)ROWS, BATCH_N - (int)row0);

    if (t < 63) s_emb[t] = emb[t];

    // Coalesced staging of stimulus indices for this block's rows.
    const int nInts = nrows * 9;
    for (int i = (int)t; i < nInts; i += TPB)
        s_stim[i] = stim[(size_t)row0 * 9 + i];
    __syncthreads();

    if ((int)t < nrows) {
        const int* st = &s_stim[t * 9];
        const int qi = st[0];
        const float qx = s_emb[qi * 3 + 0];
        const float qy = s_emb[qi * 3 + 1];
        const float qz = s_emb[qi * 3 + 2];

        float s[8];
        float total = 0.0f;
#pragma unroll
        for (int j = 0; j < 8; ++j) {
            const int ri = st[1 + j];
            const float dx = qx - s_emb[ri * 3 + 0];
            const float dy = qy - s_emb[ri * 3 + 1];
            const float dz = qz - s_emb[ri * 3 + 2];
            const float d  = sqrtf(dx * dx + dy * dy + dz * dz);
            s[j] = expf(-10.0f * d) + 0.001f;
            total += s[j];
        }
#pragma unroll
        for (int j = 0; j < 8; ++j) {
            s_sv[t][j]     = s[j];
            s_sv[t][8 + j] = s[j] / (total * (total - s[j]));  // c_j
        }
    }
    __syncthreads();

    // Cooperative coalesced write: nrows*14 float4, lane-contiguous, streaming.
    f32x4* out4 = (f32x4*)(out + (size_t)row0 * NOUT);
    const int n4 = nrows * NOUT4;
    for (int e = (int)t; e < n4; e += TPB) {
        const unsigned eu  = (unsigned)e;
        const unsigned row = eu / NOUT4;          // magic-mul
        const unsigned k4  = eu - row * NOUT4;
        const float* sv = s_sv[row];
        f32x4 v;
#pragma unroll
        for (int m = 0; m < 4; ++m) {
            const unsigned k = k4 * 4 + m;        // outcome index 0..55
            const unsigned i = k / 7u;            // first-choice ref
            const unsigned r = k - i * 7u;
            const unsigned j = r + (r >= i ? 1u : 0u);
            v[m] = sv[8 + i] * sv[j];             // c_i * s_j
        }
        __builtin_nontemporal_store(v, &out4[e]); // nt streaming store
    }
}

extern "C" void kernel_launch(void* const* d_in, const int* in_sizes, int n_in,
                              void* d_out, int out_size, void* d_ws, size_t ws_size,
                              hipStream_t stream) {
    const int*   stim = (const int*)d_in[0];    // stimulus_set (BATCH,9) int32
    const float* emb  = (const float*)d_in[1];  // embedding (21,3) f32
    float*       out  = (float*)d_out;          // (BATCH,56) f32

    const int grid = (BATCH_N + ROWS - 1) / ROWS;  // 3907
    rank_model_kernel<<<grid, TPB, 0, stream>>>(stim, emb, out);
}